// Round 2
// baseline (1116.894 us; speedup 1.0000x reference)
//
#include <hip/hip_runtime.h>
#include <stdint.h>

// ---------------- problem constants ----------------
#define B_N   1024
#define D_N   512
#define C_N   50000
#define K_N   3

#define SLABS 784                 // 192-row slabs (64 classes each), padded
#define NR    (SLABS * 192)       // 150528 weight rows (150000 real + pad)
#define GRID_G (SLABS * 8)        // 6272 gemm blocks (8 batch tiles)

#define S_SCALE 50.0f
#define COS_M   0.8775825619f     // cos(0.5)
#define SIN_M   0.4794255386f     // sin(0.5)
#define EPS_C   1e-7f

typedef __bf16 bf16_t;
typedef bf16_t bf16x8 __attribute__((ext_vector_type(8)));
typedef float  f32x4  __attribute__((ext_vector_type(4)));

__device__ __forceinline__ float wave_reduce_sum(float v) {
#pragma unroll
    for (int m = 1; m < 64; m <<= 1) v += __shfl_xor(v, m, 64);
    return v;
}

__device__ __forceinline__ void async_copy16(const void* g, void* l) {
    __builtin_amdgcn_global_load_lds(
        (const __attribute__((address_space(1))) void*)g,
        (__attribute__((address_space(3))) void*)l,
        16, 0, 0);
}

// ---------------- fused prepass: l2-normalize emb+weight rows -> bf16 ----------------
// one wave per row; weight rows written CONTIGUOUS (no K padding anymore).
__global__ void k_norm(const float* __restrict__ emb, const float* __restrict__ w,
                       bf16_t* __restrict__ En, bf16_t* __restrict__ Wn) {
    const int row  = blockIdx.x * 4 + (threadIdx.x >> 6);
    const int lane = threadIdx.x & 63;
    const float* src;
    bf16_t*      dst;
    if (row < B_N) {
        src = emb + (size_t)row * D_N;
        dst = En  + (size_t)row * D_N;
    } else {
        const int r = row - B_N;
        src = w  + (size_t)r * D_N;
        dst = Wn + (size_t)r * D_N;
    }
    const f32x4* p = (const f32x4*)(src + lane * 8);
    f32x4 a = __builtin_nontemporal_load(p);        // read-once stream: keep L3 clean
    f32x4 b = __builtin_nontemporal_load(p + 1);
    float s = a[0]*a[0] + a[1]*a[1] + a[2]*a[2] + a[3]*a[3]
            + b[0]*b[0] + b[1]*b[1] + b[2]*b[2] + b[3]*b[3];
    s = wave_reduce_sum(s);
    const float sc = 1.0f / fmaxf(sqrtf(s), 1e-12f);
    bf16x8 o;
    o[0] = (bf16_t)(a[0]*sc); o[1] = (bf16_t)(a[1]*sc);
    o[2] = (bf16_t)(a[2]*sc); o[3] = (bf16_t)(a[3]*sc);
    o[4] = (bf16_t)(b[0]*sc); o[5] = (bf16_t)(b[1]*sc);
    o[6] = (bf16_t)(b[2]*sc); o[7] = (bf16_t)(b[3]*sc);
    *(bf16x8*)(dst + lane * 8) = o;                 // cached: GEMM re-reads this
}

// ---------------- GEMM: 192 rows x 128 batch block, wave tile 96x64 ----------------
// XCD swizzle: the 8 batch-tile blocks of one slab land on one XCD -> weight slab
// is L2-resident, fetched from HBM once. Subcenter max is a barrier-free
// per-wave LDS transpose (rows -> classes) fused into the epilogue.
__global__ __launch_bounds__(256) void k_gemm(const bf16_t* __restrict__ Wn,
                                              const bf16_t* __restrict__ En,
                                              const int*    __restrict__ labels,
                                              float*        __restrict__ out) {
    __shared__ union {
        struct { bf16_t W[192][32]; bf16_t E[128][32]; } st;  // 20.0 KB staging
        float sw[4][16][100];                                 // 25.6 KB epilogue
    } sh;

    const int tid  = threadIdx.x;
    const int wave = tid >> 6, lane = tid & 63;
    const int wr = wave >> 1, wc = wave & 1;     // 2x2 wave grid: 96x64 each
    const int col = lane & 15, quad = lane >> 4;

    // grid swizzle: consecutive-8 blocks (round-robin XCDs) get 8 DIFFERENT
    // slabs; each XCD walks its own slab set with all 8 batch tiles adjacent.
    const int l  = blockIdx.x;
    const int r8 = l & 7, g = l >> 3;
    const int s  = (g >> 3) * 8 + r8;            // slab id, owned by XCD r8
    const int bt = g & 7;                        // batch tile within slab
    const size_t n0 = (size_t)s * 192;
    const int c0 = s * 64;
    const int b0 = bt * 128;

    f32x4 acc[6][4] = {};

    const int srow = lane >> 2, schunk = (lane & 3) * 8;

    for (int kk = 0; kk < D_N; kk += 32) {
        __syncthreads();
#pragma unroll
        for (int i = 0; i < 3; ++i) {            // W tile: 192 rows
            const int rb = (wave * 3 + i) * 16;
            async_copy16(Wn + (n0 + rb + srow) * D_N + kk + schunk, &sh.st.W[rb][0]);
        }
#pragma unroll
        for (int i = 0; i < 2; ++i) {            // E tile: 128 rows
            const int rb = (wave * 2 + i) * 16;
            async_copy16(En + (size_t)(b0 + rb + srow) * D_N + kk + schunk, &sh.st.E[rb][0]);
        }
        __syncthreads();

        bf16x8 af[6], bfr[4];
#pragma unroll
        for (int ti = 0; ti < 6; ++ti)
            af[ti] = *(const bf16x8*)&sh.st.W[wr * 96 + ti * 16 + col][quad * 8];
#pragma unroll
        for (int tj = 0; tj < 4; ++tj)
            bfr[tj] = *(const bf16x8*)&sh.st.E[wc * 64 + tj * 16 + col][quad * 8];

#pragma unroll
        for (int ti = 0; ti < 6; ++ti)
#pragma unroll
            for (int tj = 0; tj < 4; ++tj)
                acc[ti][tj] = __builtin_amdgcn_mfma_f32_16x16x32_bf16(
                    af[ti], bfr[tj], acc[ti][tj], 0, 0, 0);
    }

    __syncthreads();   // all staging reads done; sw may overwrite the union

    // ---- per-wave epilogue: transpose 96 rows x 16 batches at a time,
    //      max over row-triples (subcenters), margin, nt-store. Wave-local
    //      LDS hazards handled with lgkmcnt waits (no s_barrier needed).
    float* sw = &sh.sw[wave][0][0];              // [16][100]
    const int bb = lane >> 2, p = lane & 3;

#pragma unroll
    for (int tj = 0; tj < 4; ++tj) {
        asm volatile("s_waitcnt lgkmcnt(0)" ::: "memory");   // WAR vs prev reads
#pragma unroll
        for (int ti = 0; ti < 6; ++ti)
            *(f32x4*)&sw[col * 100 + ti * 16 + quad * 4] = acc[ti][tj];
        asm volatile("s_waitcnt lgkmcnt(0)" ::: "memory");   // RAW: writes visible

        const int b   = b0 + wc * 64 + tj * 16 + bb;
        const int lab = labels[b];
        const float* rowp = &sw[bb * 100 + 24 * p];          // classes 8p..8p+7
#pragma unroll
        for (int j = 0; j < 2; ++j) {
            f32x4 o;
#pragma unroll
            for (int e = 0; e < 4; ++e) {
                const int off = 12 * j + 3 * e;
                float v = fmaxf(fmaxf(rowp[off], rowp[off + 1]), rowp[off + 2]);
                const int cg = c0 + wr * 32 + 8 * p + 4 * j + e;
                if (cg == lab) {
                    float x = fminf(fmaxf(v, -1.0f + EPS_C), 1.0f - EPS_C);
                    v = x * COS_M - sqrtf(fmaxf(1.0f - x * x, 0.0f)) * SIN_M;
                }
                o[e] = S_SCALE * v;
            }
            const int cbase = c0 + wr * 32 + 8 * p + 4 * j;
            if (cbase + 3 < C_N)
                __builtin_nontemporal_store(o, (f32x4*)(out + (size_t)b * C_N + cbase));
        }
    }
}

// ---------------- fallback path (ws too small) ----------------
__global__ void k_fb_norms(const float* __restrict__ emb, const float* __restrict__ w,
                           float* __restrict__ einv, float* __restrict__ winv) {
    const int row  = blockIdx.x * 4 + (threadIdx.x >> 6);
    const int lane = threadIdx.x & 63;
    if (row >= B_N + C_N * K_N) return;
    const float* src = (row < B_N) ? (emb + (size_t)row * D_N)
                                   : (w + (size_t)(row - B_N) * D_N);
    const float4* p = (const float4*)(src + lane * 8);
    float4 a = p[0], b = p[1];
    float s = a.x*a.x + a.y*a.y + a.z*a.z + a.w*a.w
            + b.x*b.x + b.y*b.y + b.z*b.z + b.w*b.w;
    s = wave_reduce_sum(s);
    if (lane == 0) {
        float sc = 1.0f / fmaxf(sqrtf(s), 1e-12f);
        if (row < B_N) einv[row] = sc; else winv[row - B_N] = sc;
    }
}

__global__ void k_fb_gemm(const float* __restrict__ emb, const float* __restrict__ w,
                          const int* __restrict__ labels, const float* __restrict__ einv,
                          const float* __restrict__ winv, float* __restrict__ out) {
    const int b = blockIdx.x;
    const int c = blockIdx.y * 256 + threadIdx.x;
    if (c >= C_N) return;
    const float4* e4 = (const float4*)(emb + (size_t)b * D_N);
    const float es = einv[b];
    float best = -1e30f;
    for (int k = 0; k < K_N; ++k) {
        const float4* w4 = (const float4*)(w + ((size_t)c * K_N + k) * D_N);
        float dot = 0.0f;
#pragma unroll 4
        for (int d = 0; d < D_N / 4; ++d) {
            float4 a = e4[d], bb = w4[d];
            dot += a.x*bb.x + a.y*bb.y + a.z*bb.z + a.w*bb.w;
        }
        dot *= es * winv[c * K_N + k];
        best = fmaxf(best, dot);
    }
    if (c == labels[b]) {
        float x = fminf(fmaxf(best, -1.0f + EPS_C), 1.0f - EPS_C);
        best = x * COS_M - sqrtf(fmaxf(1.0f - x * x, 0.0f)) * SIN_M;
    }
    out[(size_t)b * C_N + c] = S_SCALE * best;
}

// ---------------- launch ----------------
extern "C" void kernel_launch(void* const* d_in, const int* in_sizes, int n_in,
                              void* d_out, int out_size, void* d_ws, size_t ws_size,
                              hipStream_t stream) {
    const float* emb    = (const float*)d_in[0];
    const int*   labels = (const int*)d_in[1];
    const float* weight = (const float*)d_in[2];
    float*       out    = (float*)d_out;

    const size_t offW = (size_t)1 << 20;                   // 1 MB for En
    const size_t need = offW + (size_t)NR * D_N * 2;       // + bf16 weights (~147 MB)
    if (ws_size >= need) {
        bf16_t* En = (bf16_t*)d_ws;
        bf16_t* Wn = (bf16_t*)((char*)d_ws + offW);
        k_norm<<<(B_N + C_N * K_N) / 4, 256, 0, stream>>>(emb, weight, En, Wn);
        k_gemm<<<GRID_G, 256, 0, stream>>>(Wn, En, labels, out);
    } else {
        float* einv = (float*)d_ws;
        float* winv = einv + B_N;
        k_fb_norms<<<(B_N + C_N * K_N + 3) / 4, 256, 0, stream>>>(emb, weight, einv, winv);
        k_fb_gemm<<<dim3(B_N, (C_N + 255) / 256), 256, 0, stream>>>(emb, weight, labels,
                                                                    einv, winv, out);
    }
}